// Round 5
// baseline (2026.112 us; speedup 1.0000x reference)
//
#include <hip/hip_runtime.h>
#include <hip/hip_fp16.h>

// Problem dims (fixed by reference)
#define NB 512   // batch
#define NTT 256  // timesteps
#define ND 512   // input dim
#define NH 1024  // hidden dim
#define NK 1536  // ND + NH fused K

typedef _Float16 f16;
typedef f16 f16x8 __attribute__((ext_vector_type(8)));
typedef f16 f16x4 __attribute__((ext_vector_type(4)));
typedef float f32x4 __attribute__((ext_vector_type(4)));

union U16x8 { unsigned long long q[2]; f16x8 v; uint4 u4; };

// ws layout
#define BAR_BYTES 4096                   // 16 clusters x 64 flags x 4B
#define WUT_OFF  BAR_BYTES
#define WUT_BYTES (NH * NK * 2)          // 3 MB: WUT[n][k] = k<512 ? W[k][n] : U[k-512][n]
#define H_OFF    (WUT_OFF + WUT_BYTES)
#define H_BYTES  (2 * NB * NH * 2)       // 2 MB ping-pong h

// ---------------------------------------------------------------------------
// Prep: WUT = [W;U]^T in fp16. grid = 24 (k-tiles) x 16 (n-tiles) = 384 blocks.
// ---------------------------------------------------------------------------
__global__ void prep_wut(const float* __restrict__ W, const float* __restrict__ U,
                         f16* __restrict__ WUT) {
    __shared__ float tile[64][65];
    int bk = blockIdx.x % 24, bn = blockIdx.x / 24;
    int k0 = bk * 64, n0 = bn * 64;
    int tid = threadIdx.x, jn = tid & 63;
#pragma unroll
    for (int p = 0; p < 16; ++p) {
        int kr = p * 4 + (tid >> 6);
        int k = k0 + kr;
        float v = (k < ND) ? W[(size_t)k * NH + n0 + jn] : U[(size_t)(k - ND) * NH + n0 + jn];
        tile[kr][jn] = v;
    }
    __syncthreads();
#pragma unroll
    for (int p = 0; p < 16; ++p) {
        int nr = p * 4 + (tid >> 6);
        int kc = tid & 63;
        WUT[(size_t)(n0 + nr) * NK + k0 + kc] = (f16)tile[kc][nr];
    }
}

__device__ __forceinline__ float fast_tanh(float x) {
    float e = __expf(-2.0f * x);
    return 2.0f / (1.0f + e) - 1.0f;
}

// ---------------------------------------------------------------------------
// Persistent kernel: 256 blocks x 512 threads (8 waves).
// 16 clusters of 16 blocks; cluster owns 32 batch rows; block owns 64 cols,
// weights register-resident (fused K=1536; the SAME weights serve both
// contexts). 8 waves split K 8-ways.
//
// THIS ROUND — two staggered row-CONTEXTS per block (2 x 16 rows):
//  ctx0 = cluster rows [r0, r0+16), ctx1 = [r0+16, r0+32). Each ctx has its
//  own flag array and runs the R4 per-wave producer-flag protocol
//  independently. While ctx0's publish->observe sync latency propagates,
//  the block computes ctx1 (and vice versa) — the cross-block round trips
//  hide under real work, and the CU stays busy (the prior kernel's
//  MfmaUtil/cycle arithmetic shows it ran at ~700MHz effective: DPM
//  downclock from sleep-idle waves; polls are now pure spins, no s_sleep).
//  Safety per ctx (same induction as before): a block's stores for step
//  t+1 come after its reduction __syncthreads, which rejoins all 8 waves,
//  whose polls collectively observed all 16 producer flags >= t+1 => every
//  cluster block finished READING h_t => overwriting parity t&1 is safe.
//  Contexts touch disjoint h rows.
// Reduction flattened: all 8 waves store partials (stride-21 padded bufs),
// ONE sync, every thread sums 8 bufs for (col, 2 rows) conflict-free,
// tanh+transpose, sync, coalesced 4B stores. 3 syncs per ctx.
// ---------------------------------------------------------------------------
__global__ void __launch_bounds__(512, 1)
rnn5(const float* __restrict__ x, const f16* __restrict__ WUT,
     const float* __restrict__ bias, const float* __restrict__ Wd,
     const float* __restrict__ bd, f16* __restrict__ h,
     unsigned* __restrict__ bar, float* __restrict__ out) {
    __shared__ float red[8][64][21];   // [wave][col][row16+pad5] f32, 43008 B
    __shared__ f16 trans[16][72];      // epilogue transpose, 2304 B

    const int bid = blockIdx.x, tid = threadIdx.x;
    const int lane = tid & 63, wid = tid >> 6;
    const int lrow = lane & 15, lq = lane >> 4;
    const int xcd = bid & 7, m8 = bid >> 3;
    const int cl = xcd * 2 + (m8 >> 4);     // 0..15
    const int mem = m8 & 15;                // 0..15
    const int r0 = cl * 32, c0 = mem * 64;
    const int kx0 = wid * 64;               // x k-slice base
    const int kh0 = wid * 128;              // h k-slice base (global k = 512+kh0)
    unsigned* flg = bar + cl * 64;          // [ctx*32 + mem]

    // epilogue ownership: thread -> col ec, rows er..er+1
    const int ec = tid & 63;
    const int er = (tid >> 6) * 2;
    const float bias_e = bias[c0 + ec];     // cols shared by both ctx

    // store ownership: thread -> row srow, 4B (2 cols) at sseg*2
    const int srow = tid >> 5, sseg = tid & 31;

    // ---- weights: register-resident WUT slice [c0..c0+64) x wave k-slice ----
    f16x8 bw[4][6];   // [j][kt]: kt 0..1 x-part, 2..5 h-part. 96 VGPRs.
#pragma unroll
    for (int j = 0; j < 4; ++j) {
        const int col = c0 + j * 16 + lrow;
        const f16* wp = WUT + (size_t)col * NK;
#pragma unroll
        for (int kt = 0; kt < 2; ++kt)
            bw[j][kt] = *(const f16x8*)(wp + kx0 + kt * 32 + lq * 8);
#pragma unroll
        for (int kt = 0; kt < 4; ++kt)
            bw[j][2 + kt] = *(const f16x8*)(wp + ND + kh0 + kt * 32 + lq * 8);
    }

    // ---- x prefetch for t=0, both contexts ----
    float4 xf[2][2][2];   // [ctx][kt][half]
#pragma unroll
    for (int c = 0; c < 2; ++c) {
        const float* xp = x + (size_t)(r0 + c * 16 + lrow) * (NTT * ND)
                            + kx0 + lq * 8;
#pragma unroll
        for (int kt = 0; kt < 2; ++kt) {
            xf[c][kt][0] = *(const float4*)(xp + kt * 32);
            xf[c][kt][1] = *(const float4*)(xp + kt * 32 + 4);
        }
    }

    for (int t = 0; t < NTT; ++t) {
        const f16* hprev = h + (size_t)(t & 1) * (NB * NH);
        f16* hnew = h + (size_t)((t + 1) & 1) * (NB * NH);
        const int tn = (t + 1 < NTT) ? t + 1 : NTT - 1;

#pragma unroll
        for (int c = 0; c < 2; ++c) {
            unsigned* f = flg + c * 32;

            // convert prefetched x to fragments
            f16x8 ax[2];
#pragma unroll
            for (int kt = 0; kt < 2; ++kt) {
                const float4 a = xf[c][kt][0], b = xf[c][kt][1];
                f16x8 v = {(f16)a.x, (f16)a.y, (f16)a.z, (f16)a.w,
                           (f16)b.x, (f16)b.y, (f16)b.z, (f16)b.w};
                ax[kt] = v;
            }

            f32x4 acc[4] = {};
            // x-part MFMAs (h-independent; overlap producer wait)
#pragma unroll
            for (int kt = 0; kt < 2; ++kt)
#pragma unroll
                for (int j = 0; j < 4; ++j)
                    acc[j] = __builtin_amdgcn_mfma_f32_16x16x32_f16(ax[kt], bw[j][kt], acc[j], 0, 0, 0);

            // per-wave producer wait for THIS ctx (pure spin, no sleep)
            {
                const unsigned want = (unsigned)t;
                while (__hip_atomic_load(f + 2 * wid,     __ATOMIC_RELAXED, __HIP_MEMORY_SCOPE_AGENT) < want ||
                       __hip_atomic_load(f + 2 * wid + 1, __ATOMIC_RELAXED, __HIP_MEMORY_SCOPE_AGENT) < want) {}
                __builtin_amdgcn_sched_barrier(0);   // pin h loads below poll
            }

            // h-part: agent-scope loads (cross-XCD safe), then MFMA
#pragma unroll
            for (int kt = 0; kt < 4; ++kt) {
                U16x8 a0;
                const f16* p0 = hprev + (size_t)(r0 + c * 16 + lrow) * NH + kh0 + kt * 32 + lq * 8;
                a0.q[0] = __hip_atomic_load((const unsigned long long*)p0, __ATOMIC_RELAXED, __HIP_MEMORY_SCOPE_AGENT);
                a0.q[1] = __hip_atomic_load((const unsigned long long*)p0 + 1, __ATOMIC_RELAXED, __HIP_MEMORY_SCOPE_AGENT);
#pragma unroll
                for (int j = 0; j < 4; ++j)
                    acc[j] = __builtin_amdgcn_mfma_f32_16x16x32_f16(a0.v, bw[j][2 + kt], acc[j], 0, 0, 0);
            }

            // prefetch this ctx's x for t+1 (hides under reduction/other ctx)
            {
                const float* xp = x + (size_t)(r0 + c * 16 + lrow) * (NTT * ND)
                                    + (size_t)tn * ND + kx0 + lq * 8;
#pragma unroll
                for (int kt = 0; kt < 2; ++kt) {
                    xf[c][kt][0] = *(const float4*)(xp + kt * 32);
                    xf[c][kt][1] = *(const float4*)(xp + kt * 32 + 4);
                }
            }

            // ---- flat split-K reduction: each wave stores its partial ----
#pragma unroll
            for (int j = 0; j < 4; ++j)
                *(f32x4*)&red[wid][j * 16 + lrow][lq * 4] = acc[j];
            __syncthreads();

            // ---- epilogue: thread sums 8 bufs for (ec, er..er+1) ----
            {
                float s0 = 0.f, s1 = 0.f;
#pragma unroll
                for (int b = 0; b < 8; ++b) {
                    const float2 v = *(const float2*)&red[b][ec][er];
                    s0 += v.x; s1 += v.y;
                }
                trans[er][ec]     = (f16)fast_tanh(s0 + bias_e);
                trans[er + 1][ec] = (f16)fast_tanh(s1 + bias_e);
            }
            __syncthreads();

            // ---- store h_new: 512 threads x 4B, coalesced full lines ----
            {
                const unsigned uval = *(const unsigned*)&trans[srow][sseg * 2];
                __hip_atomic_store((unsigned*)(hnew + (size_t)(r0 + c * 16 + srow) * NH + c0 + sseg * 2),
                                   uval, __ATOMIC_RELAXED, __HIP_MEMORY_SCOPE_AGENT);
            }

            // ---- arrival: drain stores (vmcnt0 at barrier), publish flag ----
            __syncthreads();
            if (tid == 0)
                __hip_atomic_store(f + mem, (unsigned)(t + 1), __ATOMIC_RELAXED, __HIP_MEMORY_SCOPE_AGENT);
        }
    }

    // ---- dense head: cluster leader computes out[r0..r0+32) ----
    if (mem == 0) {
        // wait for BOTH ctx flag arrays == NTT
        if (tid < 32) {
            unsigned* fp = flg + (tid >> 4) * 32 + (tid & 15);
            while (__hip_atomic_load(fp, __ATOMIC_RELAXED, __HIP_MEMORY_SCOPE_AGENT) < (unsigned)NTT) {}
        }
        __syncthreads();
        __builtin_amdgcn_sched_barrier(0);   // pin head loads below the wait

        const f16* hlast = h;                   // parity 0 (NTT even)
        const int r = tid >> 4, seg = tid & 15; // 32 rows x 16 segments of 64
        const f16* hp = hlast + (size_t)(r0 + r) * NH + seg * 64;
        const float* wp = Wd + seg * 64;
        float s = 0.f;
#pragma unroll
        for (int i = 0; i < 64; i += 8) {
            U16x8 u;
            u.q[0] = __hip_atomic_load((const unsigned long long*)(hp + i), __ATOMIC_RELAXED, __HIP_MEMORY_SCOPE_AGENT);
            u.q[1] = __hip_atomic_load((const unsigned long long*)(hp + i) + 1, __ATOMIC_RELAXED, __HIP_MEMORY_SCOPE_AGENT);
            const float4 w0 = *(const float4*)(wp + i);
            const float4 w1 = *(const float4*)(wp + i + 4);
            s += (float)u.v[0] * w0.x + (float)u.v[1] * w0.y +
                 (float)u.v[2] * w0.z + (float)u.v[3] * w0.w +
                 (float)u.v[4] * w1.x + (float)u.v[5] * w1.y +
                 (float)u.v[6] * w1.z + (float)u.v[7] * w1.w;
        }
        s += __shfl_xor(s, 1); s += __shfl_xor(s, 2);
        s += __shfl_xor(s, 4); s += __shfl_xor(s, 8);
        if (seg == 0) out[r0 + r] = s + bd[0];
    }
}

// ---------------------------------------------------------------------------
extern "C" void kernel_launch(void* const* d_in, const int* in_sizes, int n_in,
                              void* d_out, int out_size, void* d_ws, size_t ws_size,
                              hipStream_t stream) {
    const float* x  = (const float*)d_in[0];
    const float* W  = (const float*)d_in[1];
    const float* U  = (const float*)d_in[2];
    const float* b  = (const float*)d_in[3];
    const float* Wd = (const float*)d_in[4];
    const float* bd = (const float*)d_in[5];
    float* out = (float*)d_out;

    char* ws = (char*)d_ws;
    unsigned* bar = (unsigned*)ws;
    f16* WUT = (f16*)(ws + WUT_OFF);
    f16* h   = (f16*)(ws + H_OFF);

    hipMemsetAsync(bar, 0, BAR_BYTES, stream);
    hipMemsetAsync(h, 0, NB * NH * 2, stream);   // h_0 = 0 (parity 0)
    prep_wut<<<dim3(384), dim3(256), 0, stream>>>(W, U, WUT);

    void* args[8] = {(void*)&x, (void*)&WUT, (void*)&b, (void*)&Wd,
                     (void*)&bd, (void*)&h, (void*)&bar, (void*)&out};
    hipError_t err = hipLaunchCooperativeKernel(
        reinterpret_cast<const void*>(&rnn5), dim3(256), dim3(512), args, 0, stream);
    if (err != hipSuccess) {
        // Plain-launch fallback: 256 blocks of 8 waves fit 1/CU on 256 CUs;
        // sync is our own cluster-local atomic barrier, not cg.
        rnn5<<<dim3(256), dim3(512), 0, stream>>>(x, WUT, b, Wd, bd, h, bar, out);
    }
}